// Round 2
// baseline (3774.088 us; speedup 1.0000x reference)
//
#include <hip/hip_runtime.h>
#include <hip/hip_bf16.h>

#define T_TOK 4096
#define NEXP 8
#define HID 2048
#define INTER 4096
#define NPAIR (2 * T_TOK)   // 8192 (token,expert) pairs total

typedef unsigned int u32;
typedef unsigned short u16;
typedef short s16x8 __attribute__((ext_vector_type(8)));
typedef float f32x4 __attribute__((ext_vector_type(4)));

#define LSTRIDE 40  // u16 per LDS row: 32 payload + 8 pad (80 B, 16B-aligned, conflict-free b128 frag reads)

__device__ __forceinline__ u16 f2bf(float a) {
  u32 u = __builtin_bit_cast(u32, a);
  return (u16)((u + 0x7fffu + ((u >> 16) & 1u)) >> 16);  // RNE, no NaN inputs
}
__device__ __forceinline__ u32 pkbf(float a, float b) {
  return (u32)f2bf(a) | ((u32)f2bf(b) << 16);  // low u16 = a, high = b
}

// ---------------- routing ----------------
__global__ void zero_cnt_k(int* cnt) {
  if (threadIdx.x < NEXP) cnt[threadIdx.x] = 0;
}

__global__ void zero_out_k(float* out) {
  size_t i = ((size_t)blockIdx.x * blockDim.x + threadIdx.x) * 4;
  *(float4*)(out + i) = make_float4(0.f, 0.f, 0.f, 0.f);
}

__global__ void route_k(const float* __restrict__ logits, int* cnt,
                        int* eids, int* ranks, float* wts) {
  int t = blockIdx.x * blockDim.x + threadIdx.x;
  if (t >= T_TOK) return;
  float l[NEXP];
#pragma unroll
  for (int i = 0; i < NEXP; ++i) l[i] = logits[t * NEXP + i];
  int i0 = 0; float m0 = l[0];
#pragma unroll
  for (int i = 1; i < NEXP; ++i) if (l[i] > m0) { m0 = l[i]; i0 = i; }
  int i1 = -1; float m1 = -3.4e38f;
#pragma unroll
  for (int i = 0; i < NEXP; ++i) if (i != i0 && l[i] > m1) { m1 = l[i]; i1 = i; }
  // renormalized top-2 softmax weights: w0 = 1/(1+e^{l1-l0})
  float p1 = __expf(m1 - m0);
  float w0 = 1.f / (1.f + p1);
  float w1 = p1 * w0;
  int r0 = atomicAdd(&cnt[i0], 1);
  int r1 = atomicAdd(&cnt[i1], 1);
  eids[2 * t] = i0;  eids[2 * t + 1] = i1;
  ranks[2 * t] = r0; ranks[2 * t + 1] = r1;
  wts[2 * t] = w0;   wts[2 * t + 1] = w1;
}

__global__ void scan_k(const int* cnt, int* off) {
  if (threadIdx.x == 0 && blockIdx.x == 0) {
    int a = 0;
    for (int e = 0; e < NEXP; ++e) { off[e] = a; a += cnt[e]; }
  }
}

__global__ void place_k(const int* __restrict__ off, const int* __restrict__ eids,
                        const int* __restrict__ ranks, const float* __restrict__ wts,
                        int* __restrict__ tok, float* __restrict__ wgt) {
  int t = blockIdx.x * blockDim.x + threadIdx.x;
  if (t >= T_TOK) return;
#pragma unroll
  for (int s = 0; s < 2; ++s) {
    int e = eids[2 * t + s];
    int p = off[e] + ranks[2 * t + s];
    tok[p] = t;
    wgt[p] = wts[2 * t + s];
  }
}

// ---------------- GEMM1: A_buf = silu(Xg @ W1) * (Xg @ W3), bf16 out ----------------
// grid: e(8) x ct(64, 64 intermediate cols each -> 128 C cols gate+up) x rt(32)
__global__ __launch_bounds__(256, 2) void gemm1_k(
    const float* __restrict__ X, const float* __restrict__ W13,
    const int* __restrict__ cnt, const int* __restrict__ off,
    const int* __restrict__ tok, u16* __restrict__ Abuf) {
  const int b = blockIdx.x;
  const int rt = b & 31;
  const int ct = (b >> 5) & 63;
  const int e  = b >> 11;
  const int n_e = cnt[e];
  if (rt * 128 >= n_e) return;
  const int off_e = off[e];

  __shared__ __align__(16) u16 As[128 * LSTRIDE];
  __shared__ __align__(16) u16 Bs[128 * LSTRIDE];

  const int tid = threadIdx.x;
  const int wid = tid >> 6;
  const int lane = tid & 63;
  const int q = lane >> 4;
  const int l15 = lane & 15;

  // A staging: 2 threads/row, 16 k each (row-major, k-contiguous)
  const int arow = tid >> 1;
  const int aseg = tid & 1;
  int ridx = rt * 128 + arow;
  if (ridx >= n_e) ridx = n_e - 1;                 // clamp; masked at store
  const float* aptr = X + (size_t)tok[off_e + ridx] * HID + aseg * 16;
  u16* adst = &As[arow * LSTRIDE + aseg * 16];

  // B staging: thread handles 2 cols x 8 k, transposing into Bs[n][k]
  const int c2 = (tid & 63) * 2;                   // C-col pair 0..126
  const int kb = tid >> 6;                         // k-block of 8: 0..3
  const size_t colb = (c2 < 64) ? (size_t)(ct * 64 + c2)
                                : (size_t)(INTER + ct * 64 + (c2 - 64));
  const float* bptr = W13 + (size_t)e * ((size_t)HID * 2 * INTER) + colb;
  u16* bdst0 = &Bs[(c2 + 0) * LSTRIDE + kb * 8];
  u16* bdst1 = &Bs[(c2 + 1) * LSTRIDE + kb * 8];

  f32x4 acc[2][8];
#pragma unroll
  for (int i = 0; i < 2; ++i)
#pragma unroll
    for (int j = 0; j < 8; ++j) acc[i][j] = (f32x4){0.f, 0.f, 0.f, 0.f};

  const u16* afp = &As[(32 * wid + l15) * LSTRIDE + q * 8];
  const u16* bfp = &Bs[l15 * LSTRIDE + q * 8];

  for (int k0 = 0; k0 < HID; k0 += 32) {
    float4 a0 = *(const float4*)(aptr + k0);
    float4 a1 = *(const float4*)(aptr + k0 + 4);
    float4 a2 = *(const float4*)(aptr + k0 + 8);
    float4 a3 = *(const float4*)(aptr + k0 + 12);
    const float* bp = bptr + (size_t)(k0 + kb * 8) * (2 * INTER);
    float2 g0 = *(const float2*)(bp + 0 * (size_t)(2 * INTER));
    float2 g1 = *(const float2*)(bp + 1 * (size_t)(2 * INTER));
    float2 g2 = *(const float2*)(bp + 2 * (size_t)(2 * INTER));
    float2 g3 = *(const float2*)(bp + 3 * (size_t)(2 * INTER));
    float2 g4 = *(const float2*)(bp + 4 * (size_t)(2 * INTER));
    float2 g5 = *(const float2*)(bp + 5 * (size_t)(2 * INTER));
    float2 g6 = *(const float2*)(bp + 6 * (size_t)(2 * INTER));
    float2 g7 = *(const float2*)(bp + 7 * (size_t)(2 * INTER));
    uint4 wa0 = make_uint4(pkbf(a0.x, a0.y), pkbf(a0.z, a0.w), pkbf(a1.x, a1.y), pkbf(a1.z, a1.w));
    uint4 wa1 = make_uint4(pkbf(a2.x, a2.y), pkbf(a2.z, a2.w), pkbf(a3.x, a3.y), pkbf(a3.z, a3.w));
    uint4 wb0 = make_uint4(pkbf(g0.x, g1.x), pkbf(g2.x, g3.x), pkbf(g4.x, g5.x), pkbf(g6.x, g7.x));
    uint4 wb1 = make_uint4(pkbf(g0.y, g1.y), pkbf(g2.y, g3.y), pkbf(g4.y, g5.y), pkbf(g6.y, g7.y));
    __syncthreads();
    ((uint4*)adst)[0] = wa0;
    ((uint4*)adst)[1] = wa1;
    *(uint4*)bdst0 = wb0;
    *(uint4*)bdst1 = wb1;
    __syncthreads();
    s16x8 af0 = *(const s16x8*)(afp);
    s16x8 af1 = *(const s16x8*)(afp + 16 * LSTRIDE);
#pragma unroll
    for (int cf = 0; cf < 8; ++cf) {
      s16x8 bfv = *(const s16x8*)(bfp + 16 * cf * LSTRIDE);
      acc[0][cf] = __builtin_amdgcn_mfma_f32_16x16x32_bf16(af0, bfv, acc[0][cf], 0, 0, 0);
      acc[1][cf] = __builtin_amdgcn_mfma_f32_16x16x32_bf16(af1, bfv, acc[1][cf], 0, 0, 0);
    }
  }

  // epilogue: a = silu(gate) * up  (C cols 0..63 gate, 64..127 up), store bf16
  const int rb = rt * 128 + 32 * wid + q * 4;
#pragma unroll
  for (int rf = 0; rf < 2; ++rf) {
#pragma unroll
    for (int r = 0; r < 4; ++r) {
      const int grow = rb + 16 * rf + r;
      if (grow < n_e) {
        u16* ad = Abuf + (size_t)(off_e + grow) * INTER + (ct * 64 + l15);
#pragma unroll
        for (int cf = 0; cf < 4; ++cf) {
          float g = acc[rf][cf][r];
          float u = acc[rf][cf + 4][r];
          float a = g / (1.f + __expf(-g)) * u;
          ad[cf * 16] = f2bf(a);
        }
      }
    }
  }
}

// ---------------- GEMM2: out += w * (A_buf @ W2) ----------------
// grid: e(8) x ct(16, 128 H cols) x rt(32)
__global__ __launch_bounds__(256, 2) void gemm2_k(
    const u16* __restrict__ Abuf, const float* __restrict__ W2,
    const int* __restrict__ cnt, const int* __restrict__ off,
    const int* __restrict__ tok, const float* __restrict__ wgt,
    float* __restrict__ out) {
  const int b = blockIdx.x;
  const int rt = b & 31;
  const int ct = (b >> 5) & 15;
  const int e  = b >> 9;
  const int n_e = cnt[e];
  if (rt * 128 >= n_e) return;
  const int off_e = off[e];

  __shared__ __align__(16) u16 As[128 * LSTRIDE];
  __shared__ __align__(16) u16 Bs[128 * LSTRIDE];

  const int tid = threadIdx.x;
  const int wid = tid >> 6;
  const int lane = tid & 63;
  const int q = lane >> 4;
  const int l15 = lane & 15;

  const int arow = tid >> 1;
  const int aseg = tid & 1;
  int ridx = rt * 128 + arow;
  if (ridx >= n_e) ridx = n_e - 1;                 // stay inside this expert's segment
  const u16* aptr = Abuf + (size_t)(off_e + ridx) * INTER + aseg * 16;
  u16* adst = &As[arow * LSTRIDE + aseg * 16];

  const int c2 = (tid & 63) * 2;
  const int kb = tid >> 6;
  const float* bptr = W2 + (size_t)e * ((size_t)INTER * HID) + ct * 128 + c2;
  u16* bdst0 = &Bs[(c2 + 0) * LSTRIDE + kb * 8];
  u16* bdst1 = &Bs[(c2 + 1) * LSTRIDE + kb * 8];

  f32x4 acc[2][8];
#pragma unroll
  for (int i = 0; i < 2; ++i)
#pragma unroll
    for (int j = 0; j < 8; ++j) acc[i][j] = (f32x4){0.f, 0.f, 0.f, 0.f};

  const u16* afp = &As[(32 * wid + l15) * LSTRIDE + q * 8];
  const u16* bfp = &Bs[l15 * LSTRIDE + q * 8];

  for (int k0 = 0; k0 < INTER; k0 += 32) {
    uint4 va0 = *(const uint4*)(aptr + k0);        // already bf16
    uint4 va1 = *(const uint4*)(aptr + k0 + 8);
    const float* bp = bptr + (size_t)(k0 + kb * 8) * HID;
    float2 g0 = *(const float2*)(bp + 0 * (size_t)HID);
    float2 g1 = *(const float2*)(bp + 1 * (size_t)HID);
    float2 g2 = *(const float2*)(bp + 2 * (size_t)HID);
    float2 g3 = *(const float2*)(bp + 3 * (size_t)HID);
    float2 g4 = *(const float2*)(bp + 4 * (size_t)HID);
    float2 g5 = *(const float2*)(bp + 5 * (size_t)HID);
    float2 g6 = *(const float2*)(bp + 6 * (size_t)HID);
    float2 g7 = *(const float2*)(bp + 7 * (size_t)HID);
    uint4 wb0 = make_uint4(pkbf(g0.x, g1.x), pkbf(g2.x, g3.x), pkbf(g4.x, g5.x), pkbf(g6.x, g7.x));
    uint4 wb1 = make_uint4(pkbf(g0.y, g1.y), pkbf(g2.y, g3.y), pkbf(g4.y, g5.y), pkbf(g6.y, g7.y));
    __syncthreads();
    ((uint4*)adst)[0] = va0;
    ((uint4*)adst)[1] = va1;
    *(uint4*)bdst0 = wb0;
    *(uint4*)bdst1 = wb1;
    __syncthreads();
    s16x8 af0 = *(const s16x8*)(afp);
    s16x8 af1 = *(const s16x8*)(afp + 16 * LSTRIDE);
#pragma unroll
    for (int cf = 0; cf < 8; ++cf) {
      s16x8 bfv = *(const s16x8*)(bfp + 16 * cf * LSTRIDE);
      acc[0][cf] = __builtin_amdgcn_mfma_f32_16x16x32_bf16(af0, bfv, acc[0][cf], 0, 0, 0);
      acc[1][cf] = __builtin_amdgcn_mfma_f32_16x16x32_bf16(af1, bfv, acc[1][cf], 0, 0, 0);
    }
  }

  const int rb = rt * 128 + 32 * wid + q * 4;
#pragma unroll
  for (int rf = 0; rf < 2; ++rf) {
#pragma unroll
    for (int r = 0; r < 4; ++r) {
      const int grow = rb + 16 * rf + r;
      if (grow < n_e) {
        const int p = off_e + grow;
        const int tkn = tok[p];
        const float w = wgt[p];
        float* orow = out + (size_t)tkn * HID + ct * 128 + l15;
#pragma unroll
        for (int cf = 0; cf < 8; ++cf)
          atomicAdd(orow + cf * 16, w * acc[rf][cf][r]);
      }
    }
  }
}

extern "C" void kernel_launch(void* const* d_in, const int* in_sizes, int n_in,
                              void* d_out, int out_size, void* d_ws, size_t ws_size,
                              hipStream_t stream) {
  const float* X      = (const float*)d_in[0];   // [T, H]
  const float* logits = (const float*)d_in[1];   // [T, E]
  const float* W13    = (const float*)d_in[2];   // [E, H, 2I]
  const float* W2     = (const float*)d_in[3];   // [E, I, H]
  // d_in[4] = top_k (=2, hard-coded)
  float* out = (float*)d_out;

  char* ws = (char*)d_ws;
  int* cnt    = (int*)ws;                        // 8
  int* off    = cnt + NEXP;                      // 8
  int* eids   = off + NEXP;                      // 2T
  int* ranks  = eids + NPAIR;                    // 2T
  float* wts  = (float*)(ranks + NPAIR);         // 2T
  int* tokA   = (int*)(wts + NPAIR);             // 8192
  float* wgtA = (float*)(tokA + NPAIR);          // 8192
  u16* Abuf   = (u16*)(ws + (1 << 20));          // [8192, INTER] bf16 = 64 MiB

  zero_cnt_k<<<1, 64, 0, stream>>>(cnt);
  zero_out_k<<<(T_TOK * HID) / 1024, 256, 0, stream>>>(out);
  route_k<<<T_TOK / 256, 256, 0, stream>>>(logits, cnt, eids, ranks, wts);
  scan_k<<<1, 64, 0, stream>>>(cnt, off);
  place_k<<<T_TOK / 256, 256, 0, stream>>>(off, eids, ranks, wts, tokA, wgtA);
  gemm1_k<<<NEXP * 64 * 32, 256, 0, stream>>>(X, W13, cnt, off, tokA, Abuf);
  gemm2_k<<<NEXP * 16 * 32, 256, 0, stream>>>(Abuf, W2, cnt, off, tokA, wgtA, out);
}